// Round 2
// baseline (619.786 us; speedup 1.0000x reference)
//
#include <hip/hip_runtime.h>
#include <hip/hip_bf16.h>

typedef __bf16 bf16;
typedef __bf16 bf16x8 __attribute__((ext_vector_type(8)));
typedef __bf16 bf16x4 __attribute__((ext_vector_type(4)));
typedef float  f32x4  __attribute__((ext_vector_type(4)));

#define NB 8
#define NS 1024
#define ND 1024
#define NH 16
#define NDK 64
#define NDFF 4096
#define LDT 72   // 64 + 8 pad (144B rows, 16B aligned, 2-way banks = free)
#define LDP 40   // 32 + 8 pad

static __device__ __forceinline__ f32x4 mfma16(bf16x8 a, bf16x8 b, f32x4 c) {
    return __builtin_amdgcn_mfma_f32_16x16x32_bf16(a, b, c, 0, 0, 0);
}

// fp32 -> bf16 elementwise (n4 = count/4)
__global__ __launch_bounds__(256) void cvt_x(const float* __restrict__ in,
                                             bf16* __restrict__ out, int n4)
{
    int idx = blockIdx.x * 256 + threadIdx.x;
    if (idx >= n4) return;
    float4 v = ((const float4*)in)[idx];
    bf16x4 o = { (bf16)v.x, (bf16)v.y, (bf16)v.z, (bf16)v.w };
    ((bf16x4*)out)[idx] = o;
}

// ---------------------------------------------------------------------------
// Weight prep: fp32 src -> bf16 BT layout [N][K]; fold 0.125 into Wq (exact).
// ---------------------------------------------------------------------------
__global__ __launch_bounds__(256) void prep_transpose(
    const float* __restrict__ Wq, const float* __restrict__ Wk, const float* __restrict__ Wv,
    const float* __restrict__ Wo, const float* __restrict__ W1, const float* __restrict__ W2,
    bf16* __restrict__ wqkvT, bf16* __restrict__ WoT,
    bf16* __restrict__ W1T, bf16* __restrict__ W2T)
{
    __shared__ float T[64][65];
    int bid = blockIdx.x;
    const float* src; bf16* dst; int srcLd, dstLd, tR, tC; bool scale = false;
    if (bid < 768) {                       // Wq/Wk/Wv: per-head [1024x64] -> [64x1024]
        int mat = bid >> 4, ty = bid & 15;
        int h = mat & 15, type = mat >> 4;
        const float* W = (type == 0) ? Wq : (type == 1 ? Wk : Wv);
        src = W + (size_t)h * ND * NDK;
        srcLd = NDK; tR = ty * 64; tC = 0;
        dst = wqkvT + ((size_t)type * 1024 + h * 64) * ND;
        dstLd = ND;
        scale = (type == 0);
    } else if (bid < 1024) {               // Wo [1024x1024] -> WoT
        int b2 = bid - 768; int ty = b2 >> 4, tx = b2 & 15;
        src = Wo; srcLd = ND; tR = ty * 64; tC = tx * 64; dst = WoT; dstLd = ND;
    } else if (bid < 2048) {               // W1 [1024x4096] -> W1T [4096x1024]
        int b2 = bid - 1024; int ty = b2 >> 6, tx = b2 & 63;
        src = W1; srcLd = NDFF; tR = ty * 64; tC = tx * 64; dst = W1T; dstLd = ND;
    } else {                               // W2 [4096x1024] -> W2T [1024x4096]
        int b2 = bid - 2048; int ty = b2 >> 4, tx = b2 & 15;
        src = W2; srcLd = ND; tR = ty * 64; tC = tx * 64; dst = W2T; dstLd = NDFF;
    }
    int t = threadIdx.x;
    int c0 = t & 63, r0 = t >> 6;
    #pragma unroll
    for (int rr = 0; rr < 16; rr++) {
        int row = rr * 4 + r0;
        T[row][c0] = src[(size_t)(tR + row) * srcLd + tC + c0];
    }
    __syncthreads();
    #pragma unroll
    for (int cc = 0; cc < 16; cc++) {
        int col = cc * 4 + r0;
        float v = T[c0][col];
        if (scale) v *= 0.125f;
        dst[(size_t)(tC + col) * dstLd + tR + c0] = (bf16)v;
    }
}

__global__ void prep_bias(const float* __restrict__ bq, const float* __restrict__ bk,
                          const float* __restrict__ bv, float* __restrict__ bqkv)
{
    int n = blockIdx.x * 256 + threadIdx.x;
    if (n >= 3072) return;
    int type = n >> 10, hk = n & 1023;
    const float* bb = (type == 0) ? bq : (type == 1 ? bk : bv);
    float v = bb[hk];
    if (type == 0) v *= 0.125f;
    bqkv[n] = v;
}

// ---------------------------------------------------------------------------
// Core: C[128x128] = A[M,K] * BT[N,K]^T, bf16 in, fp32 acc. 4 waves 2x2.
// ---------------------------------------------------------------------------
__device__ __forceinline__ void gemm_bt_core(
    const bf16* __restrict__ A, const bf16* __restrict__ BT, int K,
    int rowBase, int colBase, f32x4 (&acc)[4][4], bf16* As, bf16* Bs)
{
    const int tid = threadIdx.x;
    const int lane = tid & 63, wid = tid >> 6;
    const int wr = (wid >> 1) * 64, wc = (wid & 1) * 64;
    const int lrow = lane & 15, lq = lane >> 4;
    f32x4 zz = {0.f, 0.f, 0.f, 0.f};
    #pragma unroll
    for (int i = 0; i < 4; i++)
        #pragma unroll
        for (int j = 0; j < 4; j++) acc[i][j] = zz;
    for (int k0 = 0; k0 < K; k0 += 64) {
        __syncthreads();
        #pragma unroll
        for (int c = 0; c < 4; c++) {
            int g = tid + c * 256;
            int row = g >> 3, kc = (g & 7) * 8;
            *(bf16x8*)&As[row * LDT + kc] = *(const bf16x8*)&A[(size_t)(rowBase + row) * K + k0 + kc];
            *(bf16x8*)&Bs[row * LDT + kc] = *(const bf16x8*)&BT[(size_t)(colBase + row) * K + k0 + kc];
        }
        __syncthreads();
        #pragma unroll
        for (int kh = 0; kh < 2; kh++) {
            int kof = kh * 32 + lq * 8;
            bf16x8 af[4], bfr[4];
            #pragma unroll
            for (int tt = 0; tt < 4; tt++) {
                af[tt]  = *(const bf16x8*)&As[(wr + tt * 16 + lrow) * LDT + kof];
                bfr[tt] = *(const bf16x8*)&Bs[(wc + tt * 16 + lrow) * LDT + kof];
            }
            #pragma unroll
            for (int i = 0; i < 4; i++)
                #pragma unroll
                for (int j = 0; j < 4; j++)
                    acc[i][j] = mfma16(af[i], bfr[j], acc[i][j]);
        }
    }
}

// G1: xb @ [Wq|Wk|Wv] + bias; writes Q,K row-major per (b,h); V transposed [kk][s].
__global__ __launch_bounds__(256) void g1_qkv(
    const bf16* __restrict__ x, const bf16* __restrict__ wqkvT, const float* __restrict__ bqkv,
    bf16* __restrict__ Q, bf16* __restrict__ Kb, bf16* __restrict__ Vt)
{
    __shared__ bf16 As[128 * LDT], Bs[128 * LDT];
    f32x4 acc[4][4];
    int rowBase = blockIdx.x * 128, colBase = blockIdx.y * 128;
    gemm_bt_core(x, wqkvT, ND, rowBase, colBase, acc, As, Bs);
    const int tid = threadIdx.x, lane = tid & 63, wid = tid >> 6;
    const int wr = (wid >> 1) * 64, wc = (wid & 1) * 64, lrow = lane & 15, lq = lane >> 4;
    #pragma unroll
    for (int j = 0; j < 4; j++) {
        int gcol = colBase + wc + j * 16 + lrow;
        float bias = bqkv[gcol];
        int type = gcol >> 10, h = (gcol >> 6) & 15, kk = gcol & 63;
        #pragma unroll
        for (int i = 0; i < 4; i++) {
            #pragma unroll
            for (int r = 0; r < 4; r++) {
                int grow = rowBase + wr + i * 16 + lq * 4 + r;
                int b = grow >> 10, s = grow & 1023;
                int bh = b * NH + h;
                bf16 val = (bf16)(acc[i][j][r] + bias);
                if (type == 0)      Q [((size_t)bh * NS + s) * NDK + kk] = val;
                else if (type == 1) Kb[((size_t)bh * NS + s) * NDK + kk] = val;
                else                Vt[((size_t)bh * NDK + kk) * NS + s] = val;
            }
        }
    }
}

// G2: column-softmax stats: alpha[bh][j] = mask ? 1/sum_i exp(s_ij) : 0.
__global__ __launch_bounds__(256) void g2_stats(
    const bf16* __restrict__ Q, const bf16* __restrict__ Kb,
    const int* __restrict__ mask, float* __restrict__ alpha)
{
    __shared__ bf16 Ks[128 * LDT];
    __shared__ bf16 Qs[32 * LDT];
    int bh = blockIdx.y, b = bh >> 4;
    int jBase = blockIdx.x * 128;
    const bf16* Kp = Kb + (size_t)bh * NS * NDK;
    const bf16* Qp = Q + (size_t)bh * NS * NDK;
    const int tid = threadIdx.x, lane = tid & 63, wid = tid >> 6;
    const int lrow = lane & 15, lq = lane >> 4, wj = wid * 32;
    #pragma unroll
    for (int c = 0; c < 4; c++) {
        int g = tid + c * 256, row = g >> 3, kc = (g & 7) * 8;
        *(bf16x8*)&Ks[row * LDT + kc] = *(const bf16x8*)&Kp[(size_t)(jBase + row) * NDK + kc];
    }
    float Lacc[2][4];
    #pragma unroll
    for (int jt = 0; jt < 2; jt++)
        #pragma unroll
        for (int r = 0; r < 4; r++) Lacc[jt][r] = 0.f;
    for (int i0 = 0; i0 < NS; i0 += 32) {
        __syncthreads();
        {
            int row = tid >> 3, kc = (tid & 7) * 8;
            *(bf16x8*)&Qs[row * LDT + kc] = *(const bf16x8*)&Qp[(size_t)(i0 + row) * NDK + kc];
        }
        __syncthreads();
        bf16x8 af[2][2], bq8[2][2];
        #pragma unroll
        for (int jt = 0; jt < 2; jt++)
            #pragma unroll
            for (int kh = 0; kh < 2; kh++)
                af[jt][kh] = *(const bf16x8*)&Ks[(wj + jt * 16 + lrow) * LDT + kh * 32 + lq * 8];
        #pragma unroll
        for (int it = 0; it < 2; it++)
            #pragma unroll
            for (int kh = 0; kh < 2; kh++)
                bq8[it][kh] = *(const bf16x8*)&Qs[(it * 16 + lrow) * LDT + kh * 32 + lq * 8];
        #pragma unroll
        for (int jt = 0; jt < 2; jt++) {
            #pragma unroll
            for (int it = 0; it < 2; it++) {
                f32x4 s = {0.f, 0.f, 0.f, 0.f};
                s = mfma16(af[jt][0], bq8[it][0], s);
                s = mfma16(af[jt][1], bq8[it][1], s);
                #pragma unroll
                for (int r = 0; r < 4; r++) Lacc[jt][r] += __expf(s[r]);
            }
        }
    }
    #pragma unroll
    for (int jt = 0; jt < 2; jt++) {
        #pragma unroll
        for (int r = 0; r < 4; r++) {
            float v = Lacc[jt][r];
            v += __shfl_xor(v, 1); v += __shfl_xor(v, 2);
            v += __shfl_xor(v, 4); v += __shfl_xor(v, 8);
            if (lrow == 0) {
                int j = jBase + wj + jt * 16 + lq * 4 + r;
                alpha[(size_t)bh * NS + j] = mask[b * NS + j] ? 1.f / v : 0.f;
            }
        }
    }
}

// cmask[bh][kk] = (1/S) * sum over masked j of v[j][kk]
__global__ __launch_bounds__(256) void kc_cmask(
    const bf16* __restrict__ Vt, const int* __restrict__ mask, float* __restrict__ cmask)
{
    int bh = blockIdx.x, b = bh >> 4;
    int tid = threadIdx.x;
    int kk = tid & 63, part = tid >> 6;
    const bf16* vrow = Vt + ((size_t)bh * NDK + kk) * NS;
    float s = 0.f;
    for (int j = part * 256; j < part * 256 + 256; j++)
        if (mask[b * NS + j] == 0) s += (float)vrow[j];
    __shared__ float red[256];
    red[tid] = s;
    __syncthreads();
    if (part == 0) {
        float t = red[kk] + red[kk + 64] + red[kk + 128] + red[kk + 192];
        cmask[bh * NDK + kk] = t * (1.f / 1024.f);
    }
}

// G3: ctx[i][kk] = sum_j alpha_j*exp(s_ij)*v[j][kk] + cmask[kk]
__global__ __launch_bounds__(256) void g3_ctx(
    const bf16* __restrict__ Q, const bf16* __restrict__ Kb, const bf16* __restrict__ Vt,
    const float* __restrict__ alpha, const float* __restrict__ cmask, bf16* __restrict__ ctx)
{
    __shared__ bf16 Qs[128 * LDT];
    __shared__ bf16 Ks[32 * LDT];
    __shared__ bf16 Vs[64 * LDP];
    __shared__ bf16 Ps[4 * 32 * LDP];
    int bh = blockIdx.y, iBase = blockIdx.x * 128;
    int b = bh >> 4, h = bh & 15;
    const bf16* Qp = Q + (size_t)bh * NS * NDK;
    const bf16* Kp = Kb + (size_t)bh * NS * NDK;
    const bf16* Vp = Vt + (size_t)bh * NDK * NS;
    const float* al = alpha + (size_t)bh * NS;
    const int tid = threadIdx.x, lane = tid & 63, wid = tid >> 6;
    const int lrow = lane & 15, lq = lane >> 4, wi = wid * 32;
    #pragma unroll
    for (int c = 0; c < 4; c++) {
        int g = tid + c * 256, row = g >> 3, kc = (g & 7) * 8;
        *(bf16x8*)&Qs[row * LDT + kc] = *(const bf16x8*)&Qp[(size_t)(iBase + row) * NDK + kc];
    }
    f32x4 cacc[2][4];
    f32x4 zz = {0.f, 0.f, 0.f, 0.f};
    #pragma unroll
    for (int it = 0; it < 2; it++)
        #pragma unroll
        for (int kt = 0; kt < 4; kt++) cacc[it][kt] = zz;
    bf16* Pw = Ps + wid * 32 * LDP;
    for (int j0 = 0; j0 < NS; j0 += 32) {
        __syncthreads();
        {
            int row = tid >> 3, kc = (tid & 7) * 8;
            *(bf16x8*)&Ks[row * LDT + kc] = *(const bf16x8*)&Kp[(size_t)(j0 + row) * NDK + kc];
        }
        {
            int kk = tid >> 2, ch = (tid & 3) * 8;
            *(bf16x8*)&Vs[kk * LDP + ch] = *(const bf16x8*)&Vp[(size_t)kk * NS + j0 + ch];
        }
        __syncthreads();
        bf16x8 qa[2][2], kb8[2][2];
        #pragma unroll
        for (int it = 0; it < 2; it++)
            #pragma unroll
            for (int kh = 0; kh < 2; kh++)
                qa[it][kh] = *(const bf16x8*)&Qs[(wi + it * 16 + lrow) * LDT + kh * 32 + lq * 8];
        #pragma unroll
        for (int jt = 0; jt < 2; jt++)
            #pragma unroll
            for (int kh = 0; kh < 2; kh++)
                kb8[jt][kh] = *(const bf16x8*)&Ks[(jt * 16 + lrow) * LDT + kh * 32 + lq * 8];
        float aj0 = al[j0 + lrow];
        float aj1 = al[j0 + 16 + lrow];
        #pragma unroll
        for (int it = 0; it < 2; it++) {
            #pragma unroll
            for (int jt = 0; jt < 2; jt++) {
                f32x4 s = {0.f, 0.f, 0.f, 0.f};
                s = mfma16(qa[it][0], kb8[jt][0], s);
                s = mfma16(qa[it][1], kb8[jt][1], s);
                float aj = jt ? aj1 : aj0;
                #pragma unroll
                for (int r = 0; r < 4; r++) {
                    float p = aj * __expf(s[r]);
                    Pw[(it * 16 + lq * 4 + r) * LDP + jt * 16 + lrow] = (bf16)p;
                }
            }
        }
        __syncthreads();   // order P writes before A-frag reads
        bf16x8 pa[2], vb[4];
        #pragma unroll
        for (int it = 0; it < 2; it++)
            pa[it] = *(const bf16x8*)&Pw[(it * 16 + lrow) * LDP + lq * 8];
        #pragma unroll
        for (int kt = 0; kt < 4; kt++)
            vb[kt] = *(const bf16x8*)&Vs[(kt * 16 + lrow) * LDP + lq * 8];
        #pragma unroll
        for (int it = 0; it < 2; it++)
            #pragma unroll
            for (int kt = 0; kt < 4; kt++)
                cacc[it][kt] = mfma16(pa[it], vb[kt], cacc[it][kt]);
    }
    #pragma unroll
    for (int kt = 0; kt < 4; kt++) {
        float cm = cmask[bh * NDK + kt * 16 + lrow];
        int col = h * NDK + kt * 16 + lrow;
        #pragma unroll
        for (int it = 0; it < 2; it++) {
            #pragma unroll
            for (int r = 0; r < 4; r++) {
                int i = iBase + wi + it * 16 + lq * 4 + r;
                ctx[(size_t)(b * NS + i) * ND + col] = (bf16)(cacc[it][kt][r] + cm);
            }
        }
    }
}

// G4: t1f = ctx @ Wo + bo + x  (fp32 residual stream)
__global__ __launch_bounds__(256) void g4_proj(
    const bf16* __restrict__ ctx, const bf16* __restrict__ WoT, const float* __restrict__ bo,
    const float* __restrict__ x, float* __restrict__ t1f)
{
    __shared__ bf16 As[128 * LDT], Bs[128 * LDT];
    f32x4 acc[4][4];
    int rowBase = blockIdx.x * 128, colBase = blockIdx.y * 128;
    gemm_bt_core(ctx, WoT, ND, rowBase, colBase, acc, As, Bs);
    const int tid = threadIdx.x, lane = tid & 63, wid = tid >> 6;
    const int wr = (wid >> 1) * 64, wc = (wid & 1) * 64, lrow = lane & 15, lq = lane >> 4;
    #pragma unroll
    for (int j = 0; j < 4; j++) {
        int gcol = colBase + wc + j * 16 + lrow;
        float bias = bo[gcol];
        #pragma unroll
        for (int i = 0; i < 4; i++) {
            #pragma unroll
            for (int r = 0; r < 4; r++) {
                int grow = rowBase + wr + i * 16 + lq * 4 + r;
                float v = acc[i][j][r] + bias + x[(size_t)grow * ND + gcol];
                t1f[(size_t)grow * ND + gcol] = v;
            }
        }
    }
}

// G5: hb = relu(yb @ W1 + b1)
__global__ __launch_bounds__(256) void g5_ffn1(
    const bf16* __restrict__ y, const bf16* __restrict__ W1T, const float* __restrict__ b1,
    bf16* __restrict__ hb)
{
    __shared__ bf16 As[128 * LDT], Bs[128 * LDT];
    f32x4 acc[4][4];
    int rowBase = blockIdx.x * 128, colBase = blockIdx.y * 128;
    gemm_bt_core(y, W1T, ND, rowBase, colBase, acc, As, Bs);
    const int tid = threadIdx.x, lane = tid & 63, wid = tid >> 6;
    const int wr = (wid >> 1) * 64, wc = (wid & 1) * 64, lrow = lane & 15, lq = lane >> 4;
    #pragma unroll
    for (int j = 0; j < 4; j++) {
        int gcol = colBase + wc + j * 16 + lrow;
        float bias = b1[gcol];
        #pragma unroll
        for (int i = 0; i < 4; i++) {
            #pragma unroll
            for (int r = 0; r < 4; r++) {
                int grow = rowBase + wr + i * 16 + lq * 4 + r;
                float v = fmaxf(acc[i][j][r] + bias, 0.f);
                hb[(size_t)grow * NDFF + gcol] = (bf16)v;
            }
        }
    }
}

// G6: zf = hb @ W2 + b2 + yf  (fp32, pre-LN2)
__global__ __launch_bounds__(256) void g6_ffn2(
    const bf16* __restrict__ hb, const bf16* __restrict__ W2T, const float* __restrict__ b2,
    const float* __restrict__ yf, float* __restrict__ zf)
{
    __shared__ bf16 As[128 * LDT], Bs[128 * LDT];
    f32x4 acc[4][4];
    int rowBase = blockIdx.x * 128, colBase = blockIdx.y * 128;
    gemm_bt_core(hb, W2T, NDFF, rowBase, colBase, acc, As, Bs);
    const int tid = threadIdx.x, lane = tid & 63, wid = tid >> 6;
    const int wr = (wid >> 1) * 64, wc = (wid & 1) * 64, lrow = lane & 15, lq = lane >> 4;
    #pragma unroll
    for (int j = 0; j < 4; j++) {
        int gcol = colBase + wc + j * 16 + lrow;
        float bias = b2[gcol];
        #pragma unroll
        for (int i = 0; i < 4; i++) {
            #pragma unroll
            for (int r = 0; r < 4; r++) {
                int grow = rowBase + wr + i * 16 + lq * 4 + r;
                float v = acc[i][j][r] + bias + yf[(size_t)grow * ND + gcol];
                zf[(size_t)grow * ND + gcol] = v;
            }
        }
    }
}

// Row LayerNorm over D=1024, fp32 in; writes fp32 out (+ optional bf16 out)
__global__ __launch_bounds__(256) void ln_kernel(
    const float* __restrict__ in, float* __restrict__ outf, bf16* __restrict__ outb,
    const float* __restrict__ g, const float* __restrict__ bb)
{
    int row = blockIdx.x, tid = threadIdx.x;
    const float* p = in + (size_t)row * ND;
    float4 v4 = ((const float4*)p)[tid];
    float s = v4.x + v4.y + v4.z + v4.w;
    float q = v4.x * v4.x + v4.y * v4.y + v4.z * v4.z + v4.w * v4.w;
    #pragma unroll
    for (int m = 1; m < 64; m <<= 1) { s += __shfl_xor(s, m); q += __shfl_xor(q, m); }
    __shared__ float rs[4], rq[4];
    int wid = tid >> 6, lane = tid & 63;
    if (lane == 0) { rs[wid] = s; rq[wid] = q; }
    __syncthreads();
    s = rs[0] + rs[1] + rs[2] + rs[3];
    q = rq[0] + rq[1] + rq[2] + rq[3];
    float mean = s * (1.f / 1024.f);
    float var = q * (1.f / 1024.f) - mean * mean;
    float rstd = 1.f / sqrtf(var + 1e-5f);
    float vv[4] = {v4.x, v4.y, v4.z, v4.w};
    float4 of;
    bf16x4 ob;
    #pragma unroll
    for (int k = 0; k < 4; k++) {
        int col = tid * 4 + k;
        float yv = (vv[k] - mean) * rstd * g[col] + bb[col];
        ((float*)&of)[k] = yv;
        ob[k] = (bf16)yv;
    }
    ((float4*)(outf + (size_t)row * ND))[tid] = of;
    if (outb) *(bf16x4*)&outb[(size_t)row * ND + tid * 4] = ob;
}

// ---------------------------------------------------------------------------
extern "C" void kernel_launch(void* const* d_in, const int* in_sizes, int n_in,
                              void* d_out, int out_size, void* d_ws, size_t ws_size,
                              hipStream_t stream)
{
    const float* x    = (const float*)d_in[0];
    const int*   mask = (const int*)d_in[1];
    const float* Wq   = (const float*)d_in[2];
    const float* bq   = (const float*)d_in[3];
    const float* Wk   = (const float*)d_in[4];
    const float* bk   = (const float*)d_in[5];
    const float* Wv   = (const float*)d_in[6];
    const float* bv   = (const float*)d_in[7];
    const float* Wo   = (const float*)d_in[8];
    const float* bo   = (const float*)d_in[9];
    const float* ga   = (const float*)d_in[10];
    const float* ba   = (const float*)d_in[11];
    const float* W1   = (const float*)d_in[12];
    const float* b1   = (const float*)d_in[13];
    const float* W2   = (const float*)d_in[14];
    const float* b2   = (const float*)d_in[15];
    const float* gf   = (const float*)d_in[16];
    const float* bfb  = (const float*)d_in[17];

    size_t off = 0;
    auto alloc = [&](size_t n) { char* p = (char*)d_ws + off; off += (n + 255) & ~(size_t)255; return (void*)p; };
    bf16*  wqkvT = (bf16*) alloc((size_t)3072 * 1024 * 2);           // 6 MB
    bf16*  WoT   = (bf16*) alloc((size_t)1024 * 1024 * 2);           // 2 MB
    bf16*  W1T   = (bf16*) alloc((size_t)4096 * 1024 * 2);           // 8 MB
    bf16*  W2T   = (bf16*) alloc((size_t)1024 * 4096 * 2);           // 8 MB
    float* bqkv  = (float*)alloc(3072 * 4);
    float* alpha = (float*)alloc((size_t)NB * NH * NS * 4);          // 0.5 MB
    float* cmask = (float*)alloc((size_t)NB * NH * NDK * 4);
    bf16*  xb    = (bf16*) alloc((size_t)8192 * 1024 * 2);           // 16 MB
    // 64 MB union: Qb|Kb|Vt|ctx live until g4; hb (g5/g6) aliases the whole block
    bf16*  ub    = (bf16*) alloc((size_t)8192 * 4096 * 2);           // 64 MB
    bf16*  Qb    = ub;
    bf16*  Kb    = ub + (size_t)8192 * 1024;
    bf16*  Vt    = ub + (size_t)2 * 8192 * 1024;
    bf16*  ctx   = ub + (size_t)3 * 8192 * 1024;
    bf16*  hb    = ub;
    float* t1f   = (float*)alloc((size_t)8192 * 1024 * 4);           // 32 MB (zf aliases)
    float* zf    = t1f;
    bf16*  yb    = (bf16*) alloc((size_t)8192 * 1024 * 2);           // 16 MB
    float* yf    = (float*)alloc((size_t)8192 * 1024 * 4);           // 32 MB

    cvt_x<<<8192, 256, 0, stream>>>(x, xb, 8192 * 1024 / 4);
    prep_transpose<<<3072, 256, 0, stream>>>(Wq, Wk, Wv, Wo, W1, W2, wqkvT, WoT, W1T, W2T);
    prep_bias<<<12, 256, 0, stream>>>(bq, bk, bv, bqkv);
    g1_qkv<<<dim3(64, 24), 256, 0, stream>>>(xb, wqkvT, bqkv, Qb, Kb, Vt);
    g2_stats<<<dim3(8, 128), 256, 0, stream>>>(Qb, Kb, mask, alpha);
    kc_cmask<<<128, 256, 0, stream>>>(Vt, mask, cmask);
    g3_ctx<<<dim3(8, 128), 256, 0, stream>>>(Qb, Kb, Vt, alpha, cmask, ctx);
    g4_proj<<<dim3(64, 8), 256, 0, stream>>>(ctx, WoT, bo, x, t1f);
    ln_kernel<<<8192, 256, 0, stream>>>(t1f, yf, yb, ga, ba);
    g5_ffn1<<<dim3(64, 32), 256, 0, stream>>>(yb, W1T, b1, hb);
    g6_ffn2<<<dim3(64, 8), 256, 0, stream>>>(hb, W2T, b2, yf, zf);
    ln_kernel<<<8192, 256, 0, stream>>>(zf, (float*)d_out, nullptr, gf, bfb);
}

// Round 3
// 576.094 us; speedup vs baseline: 1.0758x; 1.0758x over previous
//
#include <hip/hip_runtime.h>
#include <hip/hip_bf16.h>

typedef __bf16 bf16;
typedef __bf16 bf16x8 __attribute__((ext_vector_type(8)));
typedef __bf16 bf16x4 __attribute__((ext_vector_type(4)));
typedef float  f32x4  __attribute__((ext_vector_type(4)));

#define NB 8
#define NS 1024
#define ND 1024
#define NH 16
#define NDK 64
#define NDFF 4096
#define LDT 72   // padded stride for g2/g3 attention LDS tiles
#define LDP 40

static __device__ __forceinline__ f32x4 mfma16(bf16x8 a, bf16x8 b, f32x4 c) {
    return __builtin_amdgcn_mfma_f32_16x16x32_bf16(a, b, c, 0, 0, 0);
}

#define GLDS(g, l) __builtin_amdgcn_global_load_lds( \
    (const __attribute__((address_space(1))) void*)(g), \
    (__attribute__((address_space(3))) void*)(l), 16, 0, 0)

// fp32 -> bf16 elementwise (n4 = count/4)
__global__ __launch_bounds__(256) void cvt_x(const float* __restrict__ in,
                                             bf16* __restrict__ out, int n4)
{
    int idx = blockIdx.x * 256 + threadIdx.x;
    if (idx >= n4) return;
    float4 v = ((const float4*)in)[idx];
    bf16x4 o = { (bf16)v.x, (bf16)v.y, (bf16)v.z, (bf16)v.w };
    ((bf16x4*)out)[idx] = o;
}

// ---------------------------------------------------------------------------
// Weight prep: fp32 src -> bf16 BT layout [N][K]; fold 0.125 into Wq (exact).
// ---------------------------------------------------------------------------
__global__ __launch_bounds__(256) void prep_transpose(
    const float* __restrict__ Wq, const float* __restrict__ Wk, const float* __restrict__ Wv,
    const float* __restrict__ Wo, const float* __restrict__ W1, const float* __restrict__ W2,
    bf16* __restrict__ wqkvT, bf16* __restrict__ WoT,
    bf16* __restrict__ W1T, bf16* __restrict__ W2T)
{
    __shared__ float T[64][65];
    int bid = blockIdx.x;
    const float* src; bf16* dst; int srcLd, dstLd, tR, tC; bool scale = false;
    if (bid < 768) {                       // Wq/Wk/Wv: per-head [1024x64] -> [64x1024]
        int mat = bid >> 4, ty = bid & 15;
        int h = mat & 15, type = mat >> 4;
        const float* W = (type == 0) ? Wq : (type == 1 ? Wk : Wv);
        src = W + (size_t)h * ND * NDK;
        srcLd = NDK; tR = ty * 64; tC = 0;
        dst = wqkvT + ((size_t)type * 1024 + h * 64) * ND;
        dstLd = ND;
        scale = (type == 0);
    } else if (bid < 1024) {               // Wo [1024x1024] -> WoT
        int b2 = bid - 768; int ty = b2 >> 4, tx = b2 & 15;
        src = Wo; srcLd = ND; tR = ty * 64; tC = tx * 64; dst = WoT; dstLd = ND;
    } else if (bid < 2048) {               // W1 [1024x4096] -> W1T [4096x1024]
        int b2 = bid - 1024; int ty = b2 >> 6, tx = b2 & 63;
        src = W1; srcLd = NDFF; tR = ty * 64; tC = tx * 64; dst = W1T; dstLd = ND;
    } else {                               // W2 [4096x1024] -> W2T [1024x4096]
        int b2 = bid - 2048; int ty = b2 >> 4, tx = b2 & 15;
        src = W2; srcLd = ND; tR = ty * 64; tC = tx * 64; dst = W2T; dstLd = NDFF;
    }
    int t = threadIdx.x;
    int c0 = t & 63, r0 = t >> 6;
    #pragma unroll
    for (int rr = 0; rr < 16; rr++) {
        int row = rr * 4 + r0;
        T[row][c0] = src[(size_t)(tR + row) * srcLd + tC + c0];
    }
    __syncthreads();
    #pragma unroll
    for (int cc = 0; cc < 16; cc++) {
        int col = cc * 4 + r0;
        float v = T[c0][col];
        if (scale) v *= 0.125f;
        dst[(size_t)(tC + col) * dstLd + tR + c0] = (bf16)v;
    }
}

__global__ void prep_bias(const float* __restrict__ bq, const float* __restrict__ bk,
                          const float* __restrict__ bv, float* __restrict__ bqkv)
{
    int n = blockIdx.x * 256 + threadIdx.x;
    if (n >= 3072) return;
    int type = n >> 10, hk = n & 1023;
    const float* bb = (type == 0) ? bq : (type == 1 ? bk : bv);
    float v = bb[hk];
    if (type == 0) v *= 0.125f;
    bqkv[n] = v;
}

// ---------------------------------------------------------------------------
// Core: C[128x128] = A[M,K] * BT[N,K]^T, bf16 in, fp32 acc. 4 waves 2x2.
// global_load_lds(16B) staging, unpadded LDS, XOR-8 block swizzle.
// ---------------------------------------------------------------------------
__device__ __forceinline__ void gemm_bt_core(
    const bf16* __restrict__ A, const bf16* __restrict__ BT, int K,
    int rowBase, int colBase, f32x4 (&acc)[4][4], bf16* As, bf16* Bs)
{
    const int tid = threadIdx.x;
    const int lane = tid & 63, wid = tid >> 6;
    const int wr = (wid >> 1) * 64, wc = (wid & 1) * 64;
    const int lrow = lane & 15, lq = lane >> 4;
    // staging: wave wid covers rows [wid*32, wid*32+32), 4 issues x 8 rows.
    // LDS slot (hw-fixed): row = base + lane>>3, blk = lane&7.
    // swizzle: LDS[row][blk] = global[row][blk ^ (row&7)]
    const int srow = wid * 32 + (lane >> 3);
    const int gblk = (lane & 7) ^ ((lane >> 3) & 7);
    const bf16* Arow = A + (size_t)(rowBase + srow) * K + gblk * 8;
    const bf16* Brow = BT + (size_t)(colBase + srow) * K + gblk * 8;
    // fragment read col offsets (bf16 elems): block kb=kh*4+lq, swizzled by lrow&7
    const int co0 = ((lq) ^ (lrow & 7)) * 8;
    const int co1 = ((4 + lq) ^ (lrow & 7)) * 8;
    f32x4 zz = {0.f, 0.f, 0.f, 0.f};
    #pragma unroll
    for (int i = 0; i < 4; i++)
        #pragma unroll
        for (int j = 0; j < 4; j++) acc[i][j] = zz;
    for (int k0 = 0; k0 < K; k0 += 64) {
        __syncthreads();
        #pragma unroll
        for (int it = 0; it < 4; it++)
            GLDS(Arow + (size_t)it * 8 * K + k0, As + (wid * 32 + it * 8) * 64);
        #pragma unroll
        for (int it = 0; it < 4; it++)
            GLDS(Brow + (size_t)it * 8 * K + k0, Bs + (wid * 32 + it * 8) * 64);
        __syncthreads();
        #pragma unroll
        for (int kh = 0; kh < 2; kh++) {
            const int co = kh ? co1 : co0;
            bf16x8 af[4], bfr[4];
            #pragma unroll
            for (int tt = 0; tt < 4; tt++) {
                af[tt]  = *(const bf16x8*)&As[(wr + tt * 16 + lrow) * 64 + co];
                bfr[tt] = *(const bf16x8*)&Bs[(wc + tt * 16 + lrow) * 64 + co];
            }
            #pragma unroll
            for (int i = 0; i < 4; i++)
                #pragma unroll
                for (int j = 0; j < 4; j++)
                    acc[i][j] = mfma16(af[i], bfr[j], acc[i][j]);
        }
    }
}

// G1: xb @ [Wq|Wk|Wv] + bias; writes Q,K row-major per (b,h); V transposed [kk][s].
__global__ __launch_bounds__(256) void g1_qkv(
    const bf16* __restrict__ x, const bf16* __restrict__ wqkvT, const float* __restrict__ bqkv,
    bf16* __restrict__ Q, bf16* __restrict__ Kb, bf16* __restrict__ Vt)
{
    __shared__ bf16 As[128 * 64], Bs[128 * 64];
    f32x4 acc[4][4];
    int rowBase = blockIdx.x * 128, colBase = blockIdx.y * 128;
    gemm_bt_core(x, wqkvT, ND, rowBase, colBase, acc, As, Bs);
    const int tid = threadIdx.x, lane = tid & 63, wid = tid >> 6;
    const int wr = (wid >> 1) * 64, wc = (wid & 1) * 64, lrow = lane & 15, lq = lane >> 4;
    #pragma unroll
    for (int j = 0; j < 4; j++) {
        int gcol = colBase + wc + j * 16 + lrow;
        float bias = bqkv[gcol];
        int type = gcol >> 10, h = (gcol >> 6) & 15, kk = gcol & 63;
        #pragma unroll
        for (int i = 0; i < 4; i++) {
            #pragma unroll
            for (int r = 0; r < 4; r++) {
                int grow = rowBase + wr + i * 16 + lq * 4 + r;
                int b = grow >> 10, s = grow & 1023;
                int bh = b * NH + h;
                bf16 val = (bf16)(acc[i][j][r] + bias);
                if (type == 0)      Q [((size_t)bh * NS + s) * NDK + kk] = val;
                else if (type == 1) Kb[((size_t)bh * NS + s) * NDK + kk] = val;
                else                Vt[((size_t)bh * NDK + kk) * NS + s] = val;
            }
        }
    }
}

// G2: column-softmax stats: alpha[bh][j] = mask ? 1/sum_i exp(s_ij) : 0.
__global__ __launch_bounds__(256) void g2_stats(
    const bf16* __restrict__ Q, const bf16* __restrict__ Kb,
    const int* __restrict__ mask, float* __restrict__ alpha)
{
    __shared__ bf16 Ks[128 * LDT];
    __shared__ bf16 Qs[32 * LDT];
    int bh = blockIdx.y, b = bh >> 4;
    int jBase = blockIdx.x * 128;
    const bf16* Kp = Kb + (size_t)bh * NS * NDK;
    const bf16* Qp = Q + (size_t)bh * NS * NDK;
    const int tid = threadIdx.x, lane = tid & 63, wid = tid >> 6;
    const int lrow = lane & 15, lq = lane >> 4, wj = wid * 32;
    #pragma unroll
    for (int c = 0; c < 4; c++) {
        int g = tid + c * 256, row = g >> 3, kc = (g & 7) * 8;
        *(bf16x8*)&Ks[row * LDT + kc] = *(const bf16x8*)&Kp[(size_t)(jBase + row) * NDK + kc];
    }
    float Lacc[2][4];
    #pragma unroll
    for (int jt = 0; jt < 2; jt++)
        #pragma unroll
        for (int r = 0; r < 4; r++) Lacc[jt][r] = 0.f;
    for (int i0 = 0; i0 < NS; i0 += 32) {
        __syncthreads();
        {
            int row = tid >> 3, kc = (tid & 7) * 8;
            *(bf16x8*)&Qs[row * LDT + kc] = *(const bf16x8*)&Qp[(size_t)(i0 + row) * NDK + kc];
        }
        __syncthreads();
        bf16x8 af[2][2], bq8[2][2];
        #pragma unroll
        for (int jt = 0; jt < 2; jt++)
            #pragma unroll
            for (int kh = 0; kh < 2; kh++)
                af[jt][kh] = *(const bf16x8*)&Ks[(wj + jt * 16 + lrow) * LDT + kh * 32 + lq * 8];
        #pragma unroll
        for (int it = 0; it < 2; it++)
            #pragma unroll
            for (int kh = 0; kh < 2; kh++)
                bq8[it][kh] = *(const bf16x8*)&Qs[(it * 16 + lrow) * LDT + kh * 32 + lq * 8];
        #pragma unroll
        for (int jt = 0; jt < 2; jt++) {
            #pragma unroll
            for (int it = 0; it < 2; it++) {
                f32x4 s = {0.f, 0.f, 0.f, 0.f};
                s = mfma16(af[jt][0], bq8[it][0], s);
                s = mfma16(af[jt][1], bq8[it][1], s);
                #pragma unroll
                for (int r = 0; r < 4; r++) Lacc[jt][r] += __expf(s[r]);
            }
        }
    }
    #pragma unroll
    for (int jt = 0; jt < 2; jt++) {
        #pragma unroll
        for (int r = 0; r < 4; r++) {
            float v = Lacc[jt][r];
            v += __shfl_xor(v, 1); v += __shfl_xor(v, 2);
            v += __shfl_xor(v, 4); v += __shfl_xor(v, 8);
            if (lrow == 0) {
                int j = jBase + wj + jt * 16 + lq * 4 + r;
                alpha[(size_t)bh * NS + j] = mask[b * NS + j] ? 1.f / v : 0.f;
            }
        }
    }
}

// cmask[bh][kk] = (1/S) * sum over masked j of v[j][kk]
__global__ __launch_bounds__(256) void kc_cmask(
    const bf16* __restrict__ Vt, const int* __restrict__ mask, float* __restrict__ cmask)
{
    int bh = blockIdx.x, b = bh >> 4;
    int tid = threadIdx.x;
    int kk = tid & 63, part = tid >> 6;
    const bf16* vrow = Vt + ((size_t)bh * NDK + kk) * NS;
    float s = 0.f;
    for (int j = part * 256; j < part * 256 + 256; j++)
        if (mask[b * NS + j] == 0) s += (float)vrow[j];
    __shared__ float red[256];
    red[tid] = s;
    __syncthreads();
    if (part == 0) {
        float t = red[kk] + red[kk + 64] + red[kk + 128] + red[kk + 192];
        cmask[bh * NDK + kk] = t * (1.f / 1024.f);
    }
}

// G3: ctx[i][kk] = sum_j alpha_j*exp(s_ij)*v[j][kk] + cmask[kk]
__global__ __launch_bounds__(256) void g3_ctx(
    const bf16* __restrict__ Q, const bf16* __restrict__ Kb, const bf16* __restrict__ Vt,
    const float* __restrict__ alpha, const float* __restrict__ cmask, bf16* __restrict__ ctx)
{
    __shared__ bf16 Qs[128 * LDT];
    __shared__ bf16 Ks[32 * LDT];
    __shared__ bf16 Vs[64 * LDP];
    __shared__ bf16 Ps[4 * 32 * LDP];
    int bh = blockIdx.y, iBase = blockIdx.x * 128;
    int b = bh >> 4, h = bh & 15;
    const bf16* Qp = Q + (size_t)bh * NS * NDK;
    const bf16* Kp = Kb + (size_t)bh * NS * NDK;
    const bf16* Vp = Vt + (size_t)bh * NDK * NS;
    const float* al = alpha + (size_t)bh * NS;
    const int tid = threadIdx.x, lane = tid & 63, wid = tid >> 6;
    const int lrow = lane & 15, lq = lane >> 4, wi = wid * 32;
    #pragma unroll
    for (int c = 0; c < 4; c++) {
        int g = tid + c * 256, row = g >> 3, kc = (g & 7) * 8;
        *(bf16x8*)&Qs[row * LDT + kc] = *(const bf16x8*)&Qp[(size_t)(iBase + row) * NDK + kc];
    }
    f32x4 cacc[2][4];
    f32x4 zz = {0.f, 0.f, 0.f, 0.f};
    #pragma unroll
    for (int it = 0; it < 2; it++)
        #pragma unroll
        for (int kt = 0; kt < 4; kt++) cacc[it][kt] = zz;
    bf16* Pw = Ps + wid * 32 * LDP;
    for (int j0 = 0; j0 < NS; j0 += 32) {
        __syncthreads();
        {
            int row = tid >> 3, kc = (tid & 7) * 8;
            *(bf16x8*)&Ks[row * LDT + kc] = *(const bf16x8*)&Kp[(size_t)(j0 + row) * NDK + kc];
        }
        {
            int kk = tid >> 2, ch = (tid & 3) * 8;
            *(bf16x8*)&Vs[kk * LDP + ch] = *(const bf16x8*)&Vp[(size_t)kk * NS + j0 + ch];
        }
        __syncthreads();
        bf16x8 qa[2][2], kb8[2][2];
        #pragma unroll
        for (int it = 0; it < 2; it++)
            #pragma unroll
            for (int kh = 0; kh < 2; kh++)
                qa[it][kh] = *(const bf16x8*)&Qs[(wi + it * 16 + lrow) * LDT + kh * 32 + lq * 8];
        #pragma unroll
        for (int jt = 0; jt < 2; jt++)
            #pragma unroll
            for (int kh = 0; kh < 2; kh++)
                kb8[jt][kh] = *(const bf16x8*)&Ks[(jt * 16 + lrow) * LDT + kh * 32 + lq * 8];
        float aj0 = al[j0 + lrow];
        float aj1 = al[j0 + 16 + lrow];
        #pragma unroll
        for (int it = 0; it < 2; it++) {
            #pragma unroll
            for (int jt = 0; jt < 2; jt++) {
                f32x4 s = {0.f, 0.f, 0.f, 0.f};
                s = mfma16(qa[it][0], kb8[jt][0], s);
                s = mfma16(qa[it][1], kb8[jt][1], s);
                float aj = jt ? aj1 : aj0;
                #pragma unroll
                for (int r = 0; r < 4; r++) {
                    float p = aj * __expf(s[r]);
                    Pw[(it * 16 + lq * 4 + r) * LDP + jt * 16 + lrow] = (bf16)p;
                }
            }
        }
        __syncthreads();   // order P writes before A-frag reads
        bf16x8 pa[2], vb[4];
        #pragma unroll
        for (int it = 0; it < 2; it++)
            pa[it] = *(const bf16x8*)&Pw[(it * 16 + lrow) * LDP + lq * 8];
        #pragma unroll
        for (int kt = 0; kt < 4; kt++)
            vb[kt] = *(const bf16x8*)&Vs[(kt * 16 + lrow) * LDP + lq * 8];
        #pragma unroll
        for (int it = 0; it < 2; it++)
            #pragma unroll
            for (int kt = 0; kt < 4; kt++)
                cacc[it][kt] = mfma16(pa[it], vb[kt], cacc[it][kt]);
    }
    #pragma unroll
    for (int kt = 0; kt < 4; kt++) {
        float cm = cmask[bh * NDK + kt * 16 + lrow];
        int col = h * NDK + kt * 16 + lrow;
        #pragma unroll
        for (int it = 0; it < 2; it++) {
            #pragma unroll
            for (int r = 0; r < 4; r++) {
                int i = iBase + wi + it * 16 + lq * 4 + r;
                ctx[(size_t)(b * NS + i) * ND + col] = (bf16)(cacc[it][kt][r] + cm);
            }
        }
    }
}

// G4: t1f = ctx @ Wo + bo + x  (fp32 residual stream)
__global__ __launch_bounds__(256) void g4_proj(
    const bf16* __restrict__ ctx, const bf16* __restrict__ WoT, const float* __restrict__ bo,
    const float* __restrict__ x, float* __restrict__ t1f)
{
    __shared__ bf16 As[128 * 64], Bs[128 * 64];
    f32x4 acc[4][4];
    int rowBase = blockIdx.x * 128, colBase = blockIdx.y * 128;
    gemm_bt_core(ctx, WoT, ND, rowBase, colBase, acc, As, Bs);
    const int tid = threadIdx.x, lane = tid & 63, wid = tid >> 6;
    const int wr = (wid >> 1) * 64, wc = (wid & 1) * 64, lrow = lane & 15, lq = lane >> 4;
    #pragma unroll
    for (int j = 0; j < 4; j++) {
        int gcol = colBase + wc + j * 16 + lrow;
        float bias = bo[gcol];
        #pragma unroll
        for (int i = 0; i < 4; i++) {
            #pragma unroll
            for (int r = 0; r < 4; r++) {
                int grow = rowBase + wr + i * 16 + lq * 4 + r;
                float v = acc[i][j][r] + bias + x[(size_t)grow * ND + gcol];
                t1f[(size_t)grow * ND + gcol] = v;
            }
        }
    }
}

// G5: hb = relu(yb @ W1 + b1)
__global__ __launch_bounds__(256) void g5_ffn1(
    const bf16* __restrict__ y, const bf16* __restrict__ W1T, const float* __restrict__ b1,
    bf16* __restrict__ hb)
{
    __shared__ bf16 As[128 * 64], Bs[128 * 64];
    f32x4 acc[4][4];
    int rowBase = blockIdx.x * 128, colBase = blockIdx.y * 128;
    gemm_bt_core(y, W1T, ND, rowBase, colBase, acc, As, Bs);
    const int tid = threadIdx.x, lane = tid & 63, wid = tid >> 6;
    const int wr = (wid >> 1) * 64, wc = (wid & 1) * 64, lrow = lane & 15, lq = lane >> 4;
    #pragma unroll
    for (int j = 0; j < 4; j++) {
        int gcol = colBase + wc + j * 16 + lrow;
        float bias = b1[gcol];
        #pragma unroll
        for (int i = 0; i < 4; i++) {
            #pragma unroll
            for (int r = 0; r < 4; r++) {
                int grow = rowBase + wr + i * 16 + lq * 4 + r;
                float v = fmaxf(acc[i][j][r] + bias, 0.f);
                hb[(size_t)grow * NDFF + gcol] = (bf16)v;
            }
        }
    }
}

// G6: zf = hb @ W2 + b2 + yf  (fp32, pre-LN2)
__global__ __launch_bounds__(256) void g6_ffn2(
    const bf16* __restrict__ hb, const bf16* __restrict__ W2T, const float* __restrict__ b2,
    const float* __restrict__ yf, float* __restrict__ zf)
{
    __shared__ bf16 As[128 * 64], Bs[128 * 64];
    f32x4 acc[4][4];
    int rowBase = blockIdx.x * 128, colBase = blockIdx.y * 128;
    gemm_bt_core(hb, W2T, NDFF, rowBase, colBase, acc, As, Bs);
    const int tid = threadIdx.x, lane = tid & 63, wid = tid >> 6;
    const int wr = (wid >> 1) * 64, wc = (wid & 1) * 64, lrow = lane & 15, lq = lane >> 4;
    #pragma unroll
    for (int j = 0; j < 4; j++) {
        int gcol = colBase + wc + j * 16 + lrow;
        float bias = b2[gcol];
        #pragma unroll
        for (int i = 0; i < 4; i++) {
            #pragma unroll
            for (int r = 0; r < 4; r++) {
                int grow = rowBase + wr + i * 16 + lq * 4 + r;
                float v = acc[i][j][r] + bias + yf[(size_t)grow * ND + gcol];
                zf[(size_t)grow * ND + gcol] = v;
            }
        }
    }
}

// Row LayerNorm over D=1024, fp32 in; writes fp32 out (+ optional bf16 out)
__global__ __launch_bounds__(256) void ln_kernel(
    const float* __restrict__ in, float* __restrict__ outf, bf16* __restrict__ outb,
    const float* __restrict__ g, const float* __restrict__ bb)
{
    int row = blockIdx.x, tid = threadIdx.x;
    const float* p = in + (size_t)row * ND;
    float4 v4 = ((const float4*)p)[tid];
    float s = v4.x + v4.y + v4.z + v4.w;
    float q = v4.x * v4.x + v4.y * v4.y + v4.z * v4.z + v4.w * v4.w;
    #pragma unroll
    for (int m = 1; m < 64; m <<= 1) { s += __shfl_xor(s, m); q += __shfl_xor(q, m); }
    __shared__ float rs[4], rq[4];
    int wid = tid >> 6, lane = tid & 63;
    if (lane == 0) { rs[wid] = s; rq[wid] = q; }
    __syncthreads();
    s = rs[0] + rs[1] + rs[2] + rs[3];
    q = rq[0] + rq[1] + rq[2] + rq[3];
    float mean = s * (1.f / 1024.f);
    float var = q * (1.f / 1024.f) - mean * mean;
    float rstd = 1.f / sqrtf(var + 1e-5f);
    float vv[4] = {v4.x, v4.y, v4.z, v4.w};
    float4 of;
    bf16x4 ob;
    #pragma unroll
    for (int k = 0; k < 4; k++) {
        int col = tid * 4 + k;
        float yv = (vv[k] - mean) * rstd * g[col] + bb[col];
        ((float*)&of)[k] = yv;
        ob[k] = (bf16)yv;
    }
    ((float4*)(outf + (size_t)row * ND))[tid] = of;
    if (outb) *(bf16x4*)&outb[(size_t)row * ND + tid * 4] = ob;
}

// ---------------------------------------------------------------------------
extern "C" void kernel_launch(void* const* d_in, const int* in_sizes, int n_in,
                              void* d_out, int out_size, void* d_ws, size_t ws_size,
                              hipStream_t stream)
{
    const float* x    = (const float*)d_in[0];
    const int*   mask = (const int*)d_in[1];
    const float* Wq   = (const float*)d_in[2];
    const float* bq   = (const float*)d_in[3];
    const float* Wk   = (const float*)d_in[4];
    const float* bk   = (const float*)d_in[5];
    const float* Wv   = (const float*)d_in[6];
    const float* bv   = (const float*)d_in[7];
    const float* Wo   = (const float*)d_in[8];
    const float* bo   = (const float*)d_in[9];
    const float* ga   = (const float*)d_in[10];
    const float* ba   = (const float*)d_in[11];
    const float* W1   = (const float*)d_in[12];
    const float* b1   = (const float*)d_in[13];
    const float* W2   = (const float*)d_in[14];
    const float* b2   = (const float*)d_in[15];
    const float* gf   = (const float*)d_in[16];
    const float* bfb  = (const float*)d_in[17];

    size_t off = 0;
    auto alloc = [&](size_t n) { char* p = (char*)d_ws + off; off += (n + 255) & ~(size_t)255; return (void*)p; };
    bf16*  wqkvT = (bf16*) alloc((size_t)3072 * 1024 * 2);           // 6 MB
    bf16*  WoT   = (bf16*) alloc((size_t)1024 * 1024 * 2);           // 2 MB
    bf16*  W1T   = (bf16*) alloc((size_t)4096 * 1024 * 2);           // 8 MB
    bf16*  W2T   = (bf16*) alloc((size_t)1024 * 4096 * 2);           // 8 MB
    float* bqkv  = (float*)alloc(3072 * 4);
    float* alpha = (float*)alloc((size_t)NB * NH * NS * 4);          // 0.5 MB
    float* cmask = (float*)alloc((size_t)NB * NH * NDK * 4);
    bf16*  xb    = (bf16*) alloc((size_t)8192 * 1024 * 2);           // 16 MB
    // 64 MB union: Qb|Kb|Vt|ctx live until g4; hb (g5/g6) aliases the whole block
    bf16*  ub    = (bf16*) alloc((size_t)8192 * 4096 * 2);           // 64 MB
    bf16*  Qb    = ub;
    bf16*  Kb    = ub + (size_t)8192 * 1024;
    bf16*  Vt    = ub + (size_t)2 * 8192 * 1024;
    bf16*  ctx   = ub + (size_t)3 * 8192 * 1024;
    bf16*  hb    = ub;
    float* t1f   = (float*)alloc((size_t)8192 * 1024 * 4);           // 32 MB (zf aliases)
    float* zf    = t1f;
    bf16*  yb    = (bf16*) alloc((size_t)8192 * 1024 * 2);           // 16 MB
    float* yf    = (float*)alloc((size_t)8192 * 1024 * 4);           // 32 MB

    cvt_x<<<8192, 256, 0, stream>>>(x, xb, 8192 * 1024 / 4);
    prep_transpose<<<3072, 256, 0, stream>>>(Wq, Wk, Wv, Wo, W1, W2, wqkvT, WoT, W1T, W2T);
    prep_bias<<<12, 256, 0, stream>>>(bq, bk, bv, bqkv);
    g1_qkv<<<dim3(64, 24), 256, 0, stream>>>(xb, wqkvT, bqkv, Qb, Kb, Vt);
    g2_stats<<<dim3(8, 128), 256, 0, stream>>>(Qb, Kb, mask, alpha);
    kc_cmask<<<128, 256, 0, stream>>>(Vt, mask, cmask);
    g3_ctx<<<dim3(8, 128), 256, 0, stream>>>(Qb, Kb, Vt, alpha, cmask, ctx);
    g4_proj<<<dim3(64, 8), 256, 0, stream>>>(ctx, WoT, bo, x, t1f);
    ln_kernel<<<8192, 256, 0, stream>>>(t1f, yf, yb, ga, ba);
    g5_ffn1<<<dim3(64, 32), 256, 0, stream>>>(yb, W1T, b1, hb);
    g6_ffn2<<<dim3(64, 8), 256, 0, stream>>>(hb, W2T, b2, yf, zf);
    ln_kernel<<<8192, 256, 0, stream>>>(zf, (float*)d_out, nullptr, gf, bfb);
}

// Round 4
// 529.023 us; speedup vs baseline: 1.1716x; 1.0890x over previous
//
#include <hip/hip_runtime.h>
#include <hip/hip_bf16.h>

typedef __bf16 bf16;
typedef __bf16 bf16x8 __attribute__((ext_vector_type(8)));
typedef __bf16 bf16x4 __attribute__((ext_vector_type(4)));
typedef float  f32x4  __attribute__((ext_vector_type(4)));

#define NB 8
#define NS 1024
#define ND 1024
#define NH 16
#define NDK 64
#define NDFF 4096

static __device__ __forceinline__ f32x4 mfma16(bf16x8 a, bf16x8 b, f32x4 c) {
    return __builtin_amdgcn_mfma_f32_16x16x32_bf16(a, b, c, 0, 0, 0);
}

#define GLDS(g, l) __builtin_amdgcn_global_load_lds( \
    (const __attribute__((address_space(1))) void*)(g), \
    (__attribute__((address_space(3))) void*)(l), 16, 0, 0)

// fp32 -> bf16 elementwise (n4 = count/4)
__global__ __launch_bounds__(256) void cvt_x(const float* __restrict__ in,
                                             bf16* __restrict__ out, int n4)
{
    int idx = blockIdx.x * 256 + threadIdx.x;
    if (idx >= n4) return;
    float4 v = ((const float4*)in)[idx];
    bf16x4 o = { (bf16)v.x, (bf16)v.y, (bf16)v.z, (bf16)v.w };
    ((bf16x4*)out)[idx] = o;
}

// ---------------------------------------------------------------------------
// Weight prep: fp32 src -> bf16 BT layout [N][K]; fold 0.125 into Wq (exact).
// ---------------------------------------------------------------------------
__global__ __launch_bounds__(256) void prep_transpose(
    const float* __restrict__ Wq, const float* __restrict__ Wk, const float* __restrict__ Wv,
    const float* __restrict__ Wo, const float* __restrict__ W1, const float* __restrict__ W2,
    bf16* __restrict__ wqkvT, bf16* __restrict__ WoT,
    bf16* __restrict__ W1T, bf16* __restrict__ W2T)
{
    __shared__ float T[64][65];
    int bid = blockIdx.x;
    const float* src; bf16* dst; int srcLd, dstLd, tR, tC; bool scale = false;
    if (bid < 768) {                       // Wq/Wk/Wv: per-head [1024x64] -> [64x1024]
        int mat = bid >> 4, ty = bid & 15;
        int h = mat & 15, type = mat >> 4;
        const float* W = (type == 0) ? Wq : (type == 1 ? Wk : Wv);
        src = W + (size_t)h * ND * NDK;
        srcLd = NDK; tR = ty * 64; tC = 0;
        dst = wqkvT + ((size_t)type * 1024 + h * 64) * ND;
        dstLd = ND;
        scale = (type == 0);
    } else if (bid < 1024) {               // Wo [1024x1024] -> WoT
        int b2 = bid - 768; int ty = b2 >> 4, tx = b2 & 15;
        src = Wo; srcLd = ND; tR = ty * 64; tC = tx * 64; dst = WoT; dstLd = ND;
    } else if (bid < 2048) {               // W1 [1024x4096] -> W1T [4096x1024]
        int b2 = bid - 1024; int ty = b2 >> 6, tx = b2 & 63;
        src = W1; srcLd = NDFF; tR = ty * 64; tC = tx * 64; dst = W1T; dstLd = ND;
    } else {                               // W2 [4096x1024] -> W2T [1024x4096]
        int b2 = bid - 2048; int ty = b2 >> 4, tx = b2 & 15;
        src = W2; srcLd = ND; tR = ty * 64; tC = tx * 64; dst = W2T; dstLd = NDFF;
    }
    int t = threadIdx.x;
    int c0 = t & 63, r0 = t >> 6;
    #pragma unroll
    for (int rr = 0; rr < 16; rr++) {
        int row = rr * 4 + r0;
        T[row][c0] = src[(size_t)(tR + row) * srcLd + tC + c0];
    }
    __syncthreads();
    #pragma unroll
    for (int cc = 0; cc < 16; cc++) {
        int col = cc * 4 + r0;
        float v = T[c0][col];
        if (scale) v *= 0.125f;
        dst[(size_t)(tC + col) * dstLd + tR + c0] = (bf16)v;
    }
}

__global__ void prep_bias(const float* __restrict__ bq, const float* __restrict__ bk,
                          const float* __restrict__ bv, float* __restrict__ bqkv)
{
    int n = blockIdx.x * 256 + threadIdx.x;
    if (n >= 3072) return;
    int type = n >> 10, hk = n & 1023;
    const float* bb = (type == 0) ? bq : (type == 1 ? bk : bv);
    float v = bb[hk];
    if (type == 0) v *= 0.125f;
    bqkv[n] = v;
}

// ---------------------------------------------------------------------------
// Core: C[128x128] = A[M,K] * BT[N,K]^T, bf16 in, fp32 acc. 4 waves 2x2.
// global_load_lds(16B) staging, unpadded LDS, XOR-8 block swizzle.
// ---------------------------------------------------------------------------
__device__ __forceinline__ void gemm_bt_core(
    const bf16* __restrict__ A, const bf16* __restrict__ BT, int K,
    int rowBase, int colBase, f32x4 (&acc)[4][4], bf16* As, bf16* Bs)
{
    const int tid = threadIdx.x;
    const int lane = tid & 63, wid = tid >> 6;
    const int wr = (wid >> 1) * 64, wc = (wid & 1) * 64;
    const int lrow = lane & 15, lq = lane >> 4;
    const int srow = wid * 32 + (lane >> 3);
    const int gblk = (lane & 7) ^ ((lane >> 3) & 7);
    const bf16* Arow = A + (size_t)(rowBase + srow) * K + gblk * 8;
    const bf16* Brow = BT + (size_t)(colBase + srow) * K + gblk * 8;
    const int co0 = ((lq) ^ (lrow & 7)) * 8;
    const int co1 = ((4 + lq) ^ (lrow & 7)) * 8;
    f32x4 zz = {0.f, 0.f, 0.f, 0.f};
    #pragma unroll
    for (int i = 0; i < 4; i++)
        #pragma unroll
        for (int j = 0; j < 4; j++) acc[i][j] = zz;
    for (int k0 = 0; k0 < K; k0 += 64) {
        __syncthreads();
        #pragma unroll
        for (int it = 0; it < 4; it++)
            GLDS(Arow + (size_t)it * 8 * K + k0, As + (wid * 32 + it * 8) * 64);
        #pragma unroll
        for (int it = 0; it < 4; it++)
            GLDS(Brow + (size_t)it * 8 * K + k0, Bs + (wid * 32 + it * 8) * 64);
        __syncthreads();
        #pragma unroll
        for (int kh = 0; kh < 2; kh++) {
            const int co = kh ? co1 : co0;
            bf16x8 af[4], bfr[4];
            #pragma unroll
            for (int tt = 0; tt < 4; tt++) {
                af[tt]  = *(const bf16x8*)&As[(wr + tt * 16 + lrow) * 64 + co];
                bfr[tt] = *(const bf16x8*)&Bs[(wc + tt * 16 + lrow) * 64 + co];
            }
            #pragma unroll
            for (int i = 0; i < 4; i++)
                #pragma unroll
                for (int j = 0; j < 4; j++)
                    acc[i][j] = mfma16(af[i], bfr[j], acc[i][j]);
        }
    }
}

// G1: xb @ [Wq|Wk|Wv] + bias; Q,K,V all row-major per (b,h).
__global__ __launch_bounds__(256) void g1_qkv(
    const bf16* __restrict__ x, const bf16* __restrict__ wqkvT, const float* __restrict__ bqkv,
    bf16* __restrict__ Q, bf16* __restrict__ Kb, bf16* __restrict__ Vb)
{
    __shared__ bf16 As[128 * 64], Bs[128 * 64];
    f32x4 acc[4][4];
    int rowBase = blockIdx.x * 128, colBase = blockIdx.y * 128;
    gemm_bt_core(x, wqkvT, ND, rowBase, colBase, acc, As, Bs);
    const int tid = threadIdx.x, lane = tid & 63, wid = tid >> 6;
    const int wr = (wid >> 1) * 64, wc = (wid & 1) * 64, lrow = lane & 15, lq = lane >> 4;
    #pragma unroll
    for (int j = 0; j < 4; j++) {
        int gcol = colBase + wc + j * 16 + lrow;
        float bias = bqkv[gcol];
        int type = gcol >> 10, h = (gcol >> 6) & 15, kk = gcol & 63;
        bf16* dst = (type == 0) ? Q : (type == 1 ? Kb : Vb);
        #pragma unroll
        for (int i = 0; i < 4; i++) {
            #pragma unroll
            for (int r = 0; r < 4; r++) {
                int grow = rowBase + wr + i * 16 + lq * 4 + r;
                int b = grow >> 10, s = grow & 1023;
                int bh = b * NH + h;
                dst[((size_t)bh * NS + s) * NDK + kk] = (bf16)(acc[i][j][r] + bias);
            }
        }
    }
}

// Vb [bh][s][kk] -> Vt [bh][kk][s]  (LDS-tiled transpose)
__global__ __launch_bounds__(256) void vt_trans(
    const bf16* __restrict__ Vb, bf16* __restrict__ Vt)
{
    __shared__ bf16 T[64 * 72];
    int bh = blockIdx.y, s0 = blockIdx.x * 64;
    const bf16* src = Vb + ((size_t)bh * NS + s0) * NDK;
    int tid = threadIdx.x;
    #pragma unroll
    for (int it = 0; it < 2; it++) {
        int g = tid + it * 256;
        int row = g >> 3, c = (g & 7) * 8;
        *(bf16x8*)&T[row * 72 + c] = *(const bf16x8*)&src[row * NDK + c];
    }
    __syncthreads();
    #pragma unroll
    for (int it = 0; it < 2; it++) {
        int g = tid + it * 256;
        int kk = g >> 3, sc = (g & 7) * 8;
        bf16x8 v;
        #pragma unroll
        for (int t = 0; t < 8; t++) v[t] = T[(sc + t) * 72 + kk];
        *(bf16x8*)&Vt[((size_t)bh * NDK + kk) * NS + s0 + sc] = v;
    }
}

// G2: per-key-column coefficients: unmasked (1/sum_i exp(s_ij), 0); masked (0, 1/1024).
// j-tile 128/block, K A-frags in registers, i staged 64/step via GLDS.
__global__ __launch_bounds__(256) void g2_stats(
    const bf16* __restrict__ Q, const bf16* __restrict__ Kb,
    const int* __restrict__ mask, float2* __restrict__ alpha)
{
    __shared__ bf16 Qs[64 * 64];
    int bh = blockIdx.y, b = bh >> 4;
    int jBase = blockIdx.x * 128;
    const bf16* Kp = Kb + (size_t)bh * NS * NDK;
    const bf16* Qp = Q + (size_t)bh * NS * NDK;
    const int tid = threadIdx.x, lane = tid & 63, wid = tid >> 6;
    const int lrow = lane & 15, lq = lane >> 4;
    // K A-frags (j = jBase + wid*32 + jt*16 + lrow) held in registers
    bf16x8 kf[2][2];
    #pragma unroll
    for (int jt = 0; jt < 2; jt++)
        #pragma unroll
        for (int kh = 0; kh < 2; kh++)
            kf[jt][kh] = *(const bf16x8*)&Kp[(size_t)(jBase + wid * 32 + jt * 16 + lrow) * NDK + kh * 32 + lq * 8];
    const int srow = lane >> 3;
    const int gblk = (lane & 7) ^ srow;
    float Lacc[2][4];
    #pragma unroll
    for (int jt = 0; jt < 2; jt++)
        #pragma unroll
        for (int r = 0; r < 4; r++) Lacc[jt][r] = 0.f;
    f32x4 zz = {0.f, 0.f, 0.f, 0.f};
    for (int i0 = 0; i0 < NS; i0 += 64) {
        __syncthreads();
        #pragma unroll
        for (int it = 0; it < 2; it++)
            GLDS(Qp + (size_t)(i0 + wid * 16 + it * 8 + srow) * NDK + gblk * 8,
                 Qs + (wid * 16 + it * 8) * 64);
        __syncthreads();
        #pragma unroll
        for (int it = 0; it < 4; it++) {
            bf16x8 qb[2];
            #pragma unroll
            for (int kh = 0; kh < 2; kh++)
                qb[kh] = *(const bf16x8*)&Qs[(it * 16 + lrow) * 64 + ((kh * 4 + lq) ^ (lrow & 7)) * 8];
            #pragma unroll
            for (int jt = 0; jt < 2; jt++) {
                f32x4 s = mfma16(kf[jt][0], qb[0], zz);
                s = mfma16(kf[jt][1], qb[1], s);
                #pragma unroll
                for (int r = 0; r < 4; r++) Lacc[jt][r] += __expf(s[r]);
            }
        }
    }
    #pragma unroll
    for (int jt = 0; jt < 2; jt++) {
        #pragma unroll
        for (int r = 0; r < 4; r++) {
            float v = Lacc[jt][r];
            v += __shfl_xor(v, 1); v += __shfl_xor(v, 2);
            v += __shfl_xor(v, 4); v += __shfl_xor(v, 8);
            if (lrow == 0) {
                int j = jBase + wid * 32 + jt * 16 + lq * 4 + r;
                int m = mask[b * NS + j];
                float2 ac;
                ac.x = m ? 1.f / v : 0.f;
                ac.y = m ? 0.f : (1.f / 1024.f);
                alpha[(size_t)bh * NS + j] = ac;
            }
        }
    }
}

// G3: ctx[i][kk] = sum_j (a_j*exp(s_ij)+c_j) * v[j][kk]
// i-tile 128, Q A-frags in regs, j-step 64, P via swizzled LDS.
__global__ __launch_bounds__(256) void g3_ctx(
    const bf16* __restrict__ Q, const bf16* __restrict__ Kb, const bf16* __restrict__ Vt,
    const float2* __restrict__ alpha, bf16* __restrict__ ctx)
{
    __shared__ bf16 Ks[64 * 64];   // 8 KB
    __shared__ bf16 Vs[64 * 64];   // 8 KB
    __shared__ bf16 Ps[128 * 64];  // 16 KB, XOR-swizzled
    int bh = blockIdx.y, iBase = blockIdx.x * 128;
    int b = bh >> 4, h = bh & 15;
    const bf16* Qp = Q + (size_t)bh * NS * NDK;
    const bf16* Kp = Kb + (size_t)bh * NS * NDK;
    const bf16* Vp = Vt + (size_t)bh * NDK * NS;
    const float2* al = alpha + (size_t)bh * NS;
    const int tid = threadIdx.x, lane = tid & 63, wid = tid >> 6;
    const int lrow = lane & 15, lq = lane >> 4;
    const int wi = wid >> 1, wsub = wid & 1;
    // Q A-frags in registers: i = iBase + wi*64 + it*16 + lrow
    bf16x8 qf[4][2];
    #pragma unroll
    for (int it = 0; it < 4; it++)
        #pragma unroll
        for (int kh = 0; kh < 2; kh++)
            qf[it][kh] = *(const bf16x8*)&Qp[(size_t)(iBase + wi * 64 + it * 16 + lrow) * NDK + kh * 32 + lq * 8];
    const int srow = lane >> 3;
    const int gblk = (lane & 7) ^ srow;
    f32x4 cacc[4][2];
    f32x4 zz = {0.f, 0.f, 0.f, 0.f};
    #pragma unroll
    for (int it = 0; it < 4; it++)
        #pragma unroll
        for (int kt = 0; kt < 2; kt++) cacc[it][kt] = zz;
    for (int j0 = 0; j0 < NS; j0 += 64) {
        __syncthreads();
        #pragma unroll
        for (int it = 0; it < 2; it++)
            GLDS(Kp + (size_t)(j0 + wid * 16 + it * 8 + srow) * NDK + gblk * 8,
                 Ks + (wid * 16 + it * 8) * 64);
        #pragma unroll
        for (int it = 0; it < 2; it++)
            GLDS(Vp + (size_t)(wid * 16 + it * 8 + srow) * NS + j0 + gblk * 8,
                 Vs + (wid * 16 + it * 8) * 64);
        __syncthreads();
        // S phase: this wave: i in [wi*64, wi*64+64), j in [wsub*32, wsub*32+32)
        bf16x8 kb[2][2];
        #pragma unroll
        for (int jt = 0; jt < 2; jt++)
            #pragma unroll
            for (int kh = 0; kh < 2; kh++)
                kb[jt][kh] = *(const bf16x8*)&Ks[(wsub * 32 + jt * 16 + lrow) * 64 + ((kh * 4 + lq) ^ (lrow & 7)) * 8];
        float2 ac[2];
        ac[0] = al[j0 + wsub * 32 + lrow];
        ac[1] = al[j0 + wsub * 32 + 16 + lrow];
        #pragma unroll
        for (int it = 0; it < 4; it++) {
            #pragma unroll
            for (int jt = 0; jt < 2; jt++) {
                f32x4 s = mfma16(qf[it][0], kb[jt][0], zz);
                s = mfma16(qf[it][1], kb[jt][1], s);
                #pragma unroll
                for (int r = 0; r < 4; r++) {
                    float p = ac[jt].x * __expf(s[r]) + ac[jt].y;
                    int i = wi * 64 + it * 16 + lq * 4 + r;     // local row
                    int j = wsub * 32 + jt * 16 + lrow;         // local col
                    Ps[i * 64 + (((j >> 3) ^ (i & 7)) * 8) + (j & 7)] = (bf16)p;
                }
            }
        }
        __syncthreads();   // P writes before cross-wave P reads
        // PV phase: this wave: i in [wi*64, ..+64), kk in [wsub*32, ..+32)
        bf16x8 vb[2][2];
        #pragma unroll
        for (int kt = 0; kt < 2; kt++)
            #pragma unroll
            for (int kh = 0; kh < 2; kh++)
                vb[kt][kh] = *(const bf16x8*)&Vs[(wsub * 32 + kt * 16 + lrow) * 64 + ((kh * 4 + lq) ^ (lrow & 7)) * 8];
        #pragma unroll
        for (int it = 0; it < 4; it++) {
            bf16x8 pa[2];
            #pragma unroll
            for (int kh = 0; kh < 2; kh++)
                pa[kh] = *(const bf16x8*)&Ps[(wi * 64 + it * 16 + lrow) * 64 + ((kh * 4 + lq) ^ (lrow & 7)) * 8];
            #pragma unroll
            for (int kt = 0; kt < 2; kt++) {
                cacc[it][kt] = mfma16(pa[0], vb[kt][0], cacc[it][kt]);
                cacc[it][kt] = mfma16(pa[1], vb[kt][1], cacc[it][kt]);
            }
        }
    }
    #pragma unroll
    for (int kt = 0; kt < 2; kt++) {
        int col = h * NDK + wsub * 32 + kt * 16 + lrow;
        #pragma unroll
        for (int it = 0; it < 4; it++) {
            #pragma unroll
            for (int r = 0; r < 4; r++) {
                int i = iBase + wi * 64 + it * 16 + lq * 4 + r;
                ctx[(size_t)(b * NS + i) * ND + col] = (bf16)cacc[it][kt][r];
            }
        }
    }
}

// G4: t1f = ctx @ Wo + bo + x  (fp32 residual stream)
__global__ __launch_bounds__(256) void g4_proj(
    const bf16* __restrict__ ctx, const bf16* __restrict__ WoT, const float* __restrict__ bo,
    const float* __restrict__ x, float* __restrict__ t1f)
{
    __shared__ bf16 As[128 * 64], Bs[128 * 64];
    f32x4 acc[4][4];
    int rowBase = blockIdx.x * 128, colBase = blockIdx.y * 128;
    gemm_bt_core(ctx, WoT, ND, rowBase, colBase, acc, As, Bs);
    const int tid = threadIdx.x, lane = tid & 63, wid = tid >> 6;
    const int wr = (wid >> 1) * 64, wc = (wid & 1) * 64, lrow = lane & 15, lq = lane >> 4;
    #pragma unroll
    for (int j = 0; j < 4; j++) {
        int gcol = colBase + wc + j * 16 + lrow;
        float bias = bo[gcol];
        #pragma unroll
        for (int i = 0; i < 4; i++) {
            #pragma unroll
            for (int r = 0; r < 4; r++) {
                int grow = rowBase + wr + i * 16 + lq * 4 + r;
                float v = acc[i][j][r] + bias + x[(size_t)grow * ND + gcol];
                t1f[(size_t)grow * ND + gcol] = v;
            }
        }
    }
}

// G5: hb = relu(yb @ W1 + b1)
__global__ __launch_bounds__(256) void g5_ffn1(
    const bf16* __restrict__ y, const bf16* __restrict__ W1T, const float* __restrict__ b1,
    bf16* __restrict__ hb)
{
    __shared__ bf16 As[128 * 64], Bs[128 * 64];
    f32x4 acc[4][4];
    int rowBase = blockIdx.x * 128, colBase = blockIdx.y * 128;
    gemm_bt_core(y, W1T, ND, rowBase, colBase, acc, As, Bs);
    const int tid = threadIdx.x, lane = tid & 63, wid = tid >> 6;
    const int wr = (wid >> 1) * 64, wc = (wid & 1) * 64, lrow = lane & 15, lq = lane >> 4;
    #pragma unroll
    for (int j = 0; j < 4; j++) {
        int gcol = colBase + wc + j * 16 + lrow;
        float bias = b1[gcol];
        #pragma unroll
        for (int i = 0; i < 4; i++) {
            #pragma unroll
            for (int r = 0; r < 4; r++) {
                int grow = rowBase + wr + i * 16 + lq * 4 + r;
                float v = fmaxf(acc[i][j][r] + bias, 0.f);
                hb[(size_t)grow * NDFF + gcol] = (bf16)v;
            }
        }
    }
}

// G6: zf = hb @ W2 + b2 + yf  (fp32, pre-LN2)
__global__ __launch_bounds__(256) void g6_ffn2(
    const bf16* __restrict__ hb, const bf16* __restrict__ W2T, const float* __restrict__ b2,
    const float* __restrict__ yf, float* __restrict__ zf)
{
    __shared__ bf16 As[128 * 64], Bs[128 * 64];
    f32x4 acc[4][4];
    int rowBase = blockIdx.x * 128, colBase = blockIdx.y * 128;
    gemm_bt_core(hb, W2T, NDFF, rowBase, colBase, acc, As, Bs);
    const int tid = threadIdx.x, lane = tid & 63, wid = tid >> 6;
    const int wr = (wid >> 1) * 64, wc = (wid & 1) * 64, lrow = lane & 15, lq = lane >> 4;
    #pragma unroll
    for (int j = 0; j < 4; j++) {
        int gcol = colBase + wc + j * 16 + lrow;
        float bias = b2[gcol];
        #pragma unroll
        for (int i = 0; i < 4; i++) {
            #pragma unroll
            for (int r = 0; r < 4; r++) {
                int grow = rowBase + wr + i * 16 + lq * 4 + r;
                float v = acc[i][j][r] + bias + yf[(size_t)grow * ND + gcol];
                zf[(size_t)grow * ND + gcol] = v;
            }
        }
    }
}

// Row LayerNorm over D=1024, fp32 in; writes fp32 out (+ optional bf16 out)
__global__ __launch_bounds__(256) void ln_kernel(
    const float* __restrict__ in, float* __restrict__ outf, bf16* __restrict__ outb,
    const float* __restrict__ g, const float* __restrict__ bb)
{
    int row = blockIdx.x, tid = threadIdx.x;
    const float* p = in + (size_t)row * ND;
    float4 v4 = ((const float4*)p)[tid];
    float s = v4.x + v4.y + v4.z + v4.w;
    float q = v4.x * v4.x + v4.y * v4.y + v4.z * v4.z + v4.w * v4.w;
    #pragma unroll
    for (int m = 1; m < 64; m <<= 1) { s += __shfl_xor(s, m); q += __shfl_xor(q, m); }
    __shared__ float rs[4], rq[4];
    int wid = tid >> 6, lane = tid & 63;
    if (lane == 0) { rs[wid] = s; rq[wid] = q; }
    __syncthreads();
    s = rs[0] + rs[1] + rs[2] + rs[3];
    q = rq[0] + rq[1] + rq[2] + rq[3];
    float mean = s * (1.f / 1024.f);
    float var = q * (1.f / 1024.f) - mean * mean;
    float rstd = 1.f / sqrtf(var + 1e-5f);
    float vv[4] = {v4.x, v4.y, v4.z, v4.w};
    float4 of;
    bf16x4 ob;
    #pragma unroll
    for (int k = 0; k < 4; k++) {
        int col = tid * 4 + k;
        float yv = (vv[k] - mean) * rstd * g[col] + bb[col];
        ((float*)&of)[k] = yv;
        ob[k] = (bf16)yv;
    }
    ((float4*)(outf + (size_t)row * ND))[tid] = of;
    if (outb) *(bf16x4*)&outb[(size_t)row * ND + tid * 4] = ob;
}

// ---------------------------------------------------------------------------
extern "C" void kernel_launch(void* const* d_in, const int* in_sizes, int n_in,
                              void* d_out, int out_size, void* d_ws, size_t ws_size,
                              hipStream_t stream)
{
    const float* x    = (const float*)d_in[0];
    const int*   mask = (const int*)d_in[1];
    const float* Wq   = (const float*)d_in[2];
    const float* bq   = (const float*)d_in[3];
    const float* Wk   = (const float*)d_in[4];
    const float* bk   = (const float*)d_in[5];
    const float* Wv   = (const float*)d_in[6];
    const float* bv   = (const float*)d_in[7];
    const float* Wo   = (const float*)d_in[8];
    const float* bo   = (const float*)d_in[9];
    const float* ga   = (const float*)d_in[10];
    const float* ba   = (const float*)d_in[11];
    const float* W1   = (const float*)d_in[12];
    const float* b1   = (const float*)d_in[13];
    const float* W2   = (const float*)d_in[14];
    const float* b2   = (const float*)d_in[15];
    const float* gf   = (const float*)d_in[16];
    const float* bfb  = (const float*)d_in[17];

    size_t off = 0;
    auto alloc = [&](size_t n) { char* p = (char*)d_ws + off; off += (n + 255) & ~(size_t)255; return (void*)p; };
    bf16*   wqkvT = (bf16*)  alloc((size_t)3072 * 1024 * 2);           // 6 MB
    bf16*   WoT   = (bf16*)  alloc((size_t)1024 * 1024 * 2);           // 2 MB
    bf16*   W1T   = (bf16*)  alloc((size_t)4096 * 1024 * 2);           // 8 MB
    bf16*   W2T   = (bf16*)  alloc((size_t)1024 * 4096 * 2);           // 8 MB
    float*  bqkv  = (float*) alloc(3072 * 4);
    float2* alpha = (float2*)alloc((size_t)NB * NH * NS * 8);          // 1 MB
    bf16*   xb    = (bf16*)  alloc((size_t)8192 * 1024 * 2);           // 16 MB
    // 64 MB union: Qb|Kb|Vt|ctx live until g4; hb (g5/g6) aliases the whole block
    bf16*   ub    = (bf16*)  alloc((size_t)8192 * 4096 * 2);           // 64 MB
    bf16*   Qb    = ub;
    bf16*   Kb    = ub + (size_t)8192 * 1024;
    bf16*   Vt    = ub + (size_t)2 * 8192 * 1024;
    bf16*   ctx   = ub + (size_t)3 * 8192 * 1024;
    bf16*   hb    = ub;
    float*  t1f   = (float*) alloc((size_t)8192 * 1024 * 4);           // 32 MB (zf, Vb alias)
    float*  zf    = t1f;
    bf16*   Vb    = (bf16*)t1f;   // dead before g4 writes t1f
    bf16*   yb    = (bf16*)  alloc((size_t)8192 * 1024 * 2);           // 16 MB
    float*  yf    = (float*) alloc((size_t)8192 * 1024 * 4);           // 32 MB

    cvt_x<<<8192, 256, 0, stream>>>(x, xb, 8192 * 1024 / 4);
    prep_transpose<<<3072, 256, 0, stream>>>(Wq, Wk, Wv, Wo, W1, W2, wqkvT, WoT, W1T, W2T);
    prep_bias<<<12, 256, 0, stream>>>(bq, bk, bv, bqkv);
    g1_qkv<<<dim3(64, 24), 256, 0, stream>>>(xb, wqkvT, bqkv, Qb, Kb, Vb);
    vt_trans<<<dim3(16, 128), 256, 0, stream>>>(Vb, Vt);
    g2_stats<<<dim3(8, 128), 256, 0, stream>>>(Qb, Kb, mask, alpha);
    g3_ctx<<<dim3(8, 128), 256, 0, stream>>>(Qb, Kb, Vt, alpha, ctx);
    g4_proj<<<dim3(64, 8), 256, 0, stream>>>(ctx, WoT, bo, x, t1f);
    ln_kernel<<<8192, 256, 0, stream>>>(t1f, yf, yb, ga, ba);
    g5_ffn1<<<dim3(64, 32), 256, 0, stream>>>(yb, W1T, b1, hb);
    g6_ffn2<<<dim3(64, 8), 256, 0, stream>>>(hb, W2T, b2, yf, zf);
    ln_kernel<<<8192, 256, 0, stream>>>(zf, (float*)d_out, nullptr, gf, bfb);
}